// Round 1
// baseline (662.071 us; speedup 1.0000x reference)
//
#include <hip/hip_runtime.h>
#include <math.h>

#define B_    8
#define L_    4096
#define NROWS (B_*L_)      // 32768
#define CDIM  512
#define G_    2
#define V_    320
#define NCOLS (G_*V_)      // 640
#define DCODE 128
#define TM    16

// Fused: logits GEMM + bias + noise-free softmax (block-partial mean) +
// gumbel argmax + codevector gather.
__global__ __launch_bounds__(256) void gvq_main(
    const float* __restrict__ hidden,    // [32768,512]
    const float* __restrict__ gumbel_u,  // [65536,320]
    const float* __restrict__ w,         // [512,640]
    const float* __restrict__ bias,      // [640]
    const float* __restrict__ cv,        // [640,128]
    float* __restrict__ out,             // [32768,256] (+ perplexity at end, other kernel)
    float* __restrict__ gavg)            // [640] global accumulator (ws)
{
    __shared__ float smem[TM*NCOLS + NCOLS];  // 16*640 logits (first 16*512 doubles as h-tile) + 640 avg
    float* sh   = smem;            // h tile [16][512] flat
    float* slog = smem;            // logits [16][640] flat (reused after GEMM)
    float* savg = smem + TM*NCOLS; // [640] block-partial softmax sums

    const int t  = threadIdx.x;
    const int bi = blockIdx.x;
    const int n0 = bi * TM;

    // zero block-partial accumulator (disjoint from h region)
    for (int v = t; v < NCOLS; v += 256) savg[v] = 0.f;

    // ---- stage hidden tile: 16 rows x 512 f32, coalesced float4 ----
    {
        const float4* hsrc = (const float4*)(hidden + (size_t)n0 * CDIM);
        float4* hdst = (float4*)sh;
        #pragma unroll
        for (int i = 0; i < (TM*CDIM/4)/256; ++i)   // 8 iters
            hdst[t + i*256] = hsrc[t + i*256];
    }
    __syncthreads();

    // ---- GEMM: each thread = 4 rows x 10 cols (cols 2*cg + 128*j + {0,1}) ----
    const int cg = t & 63;   // wave = one row-group -> h reads broadcast
    const int rg = t >> 6;

    float2 acc[4][5];
    #pragma unroll
    for (int i = 0; i < 4; ++i)
        #pragma unroll
        for (int j = 0; j < 5; ++j) acc[i][j] = make_float2(0.f, 0.f);

    const float* wbase = w + 2*cg;
    for (int k0 = 0; k0 < CDIM; k0 += 4) {
        float4 hv[4];
        #pragma unroll
        for (int i = 0; i < 4; ++i)
            hv[i] = *(const float4*)&sh[(rg*4 + i)*CDIM + k0];
        #pragma unroll
        for (int kk = 0; kk < 4; ++kk) {
            float2 wv[5];
            #pragma unroll
            for (int j = 0; j < 5; ++j)
                wv[j] = *(const float2*)&wbase[(size_t)(k0 + kk)*NCOLS + 128*j];
            #pragma unroll
            for (int i = 0; i < 4; ++i) {
                float h = ((const float*)&hv[i])[kk];
                #pragma unroll
                for (int j = 0; j < 5; ++j) {
                    acc[i][j].x = fmaf(h, wv[j].x, acc[i][j].x);
                    acc[i][j].y = fmaf(h, wv[j].y, acc[i][j].y);
                }
            }
        }
    }
    __syncthreads();   // everyone done reading sh

    // ---- logits + bias -> LDS ----
    #pragma unroll
    for (int j = 0; j < 5; ++j) {
        float2 bv = *(const float2*)&bias[2*cg + 128*j];
        #pragma unroll
        for (int i = 0; i < 4; ++i) {
            float2 v = acc[i][j];
            v.x += bv.x; v.y += bv.y;
            *(float2*)&slog[(rg*4 + i)*NCOLS + 2*cg + 128*j] = v;
        }
    }
    __syncthreads();

    // ---- per-(row,group) tasks: 32 tasks, 8 per wave ----
    const int wave = t >> 6;
    const int lane = t & 63;
    for (int s = 0; s < 8; ++s) {
        const int task = wave*8 + s;
        const int r = task >> 1, g = task & 1;
        const int n = n0 + r;

        float z[5];
        #pragma unroll
        for (int j = 0; j < 5; ++j) z[j] = slog[r*NCOLS + g*V_ + lane + 64*j];

        // noise-free softmax -> block-partial mean accumulation
        float m = z[0];
        #pragma unroll
        for (int j = 1; j < 5; ++j) m = fmaxf(m, z[j]);
        #pragma unroll
        for (int o = 32; o >= 1; o >>= 1) m = fmaxf(m, __shfl_xor(m, o));
        float e[5], ss = 0.f;
        #pragma unroll
        for (int j = 0; j < 5; ++j) { e[j] = expf(z[j] - m); ss += e[j]; }
        #pragma unroll
        for (int o = 32; o >= 1; o >>= 1) ss += __shfl_xor(ss, o);
        const float inv = 1.f / ss;
        #pragma unroll
        for (int j = 0; j < 5; ++j)
            atomicAdd(&savg[g*V_ + lane + 64*j], e[j] * inv);

        // gumbel argmax (first-index tie-break, matches jnp.argmax)
        const float* up = gumbel_u + ((size_t)n*G_ + g)*V_;
        float best = -INFINITY; int bidx = 0;
        #pragma unroll
        for (int j = 0; j < 5; ++j) {
            float un  = up[lane + 64*j];
            float gum = -logf(-logf(un + 1e-10f) + 1e-10f);
            float nv  = z[j] + gum;
            if (nv > best) { best = nv; bidx = lane + 64*j; }  // ascending j => earliest v on tie
        }
        #pragma unroll
        for (int o = 1; o < 64; o <<= 1) {
            float ov = __shfl_xor(best, o);
            int   oi = __shfl_xor(bidx, o);
            if (ov > best || (ov == best && oi < bidx)) { best = ov; bidx = oi; }
        }

        // gather codevector row (128 f32 = 64 lanes x float2)
        const float2* cvp = (const float2*)&cv[((size_t)g*V_ + bidx)*DCODE];
        float2 val = cvp[lane];
        ((float2*)&out[(size_t)n*(G_*DCODE) + g*DCODE])[lane] = val;
    }
    __syncthreads();

    // block partial -> global
    for (int v = t; v < NCOLS; v += 256) atomicAdd(&gavg[v], savg[v]);
}

__global__ __launch_bounds__(64) void gvq_perp(const float* __restrict__ gavg,
                                               float* __restrict__ out)
{
    const int lane = threadIdx.x;
    float s0 = 0.f, s1 = 0.f;
    for (int v = lane; v < V_; v += 64) {
        float p0 = gavg[v]      * (1.f / NROWS);
        float p1 = gavg[V_ + v] * (1.f / NROWS);
        s0 += p0 * logf(p0 + 1e-7f);
        s1 += p1 * logf(p1 + 1e-7f);
    }
    #pragma unroll
    for (int o = 32; o >= 1; o >>= 1) {
        s0 += __shfl_xor(s0, o);
        s1 += __shfl_xor(s1, o);
    }
    if (lane == 0)
        out[(size_t)NROWS * (G_*DCODE)] = expf(-s0) + expf(-s1);
}

extern "C" void kernel_launch(void* const* d_in, const int* in_sizes, int n_in,
                              void* d_out, int out_size, void* d_ws, size_t ws_size,
                              hipStream_t stream)
{
    const float* hidden = (const float*)d_in[0];
    const float* gu     = (const float*)d_in[1];
    const float* w      = (const float*)d_in[2];
    const float* b      = (const float*)d_in[3];
    const float* cv     = (const float*)d_in[4];
    float* out  = (float*)d_out;
    float* gavg = (float*)d_ws;

    hipMemsetAsync(d_ws, 0, NCOLS * sizeof(float), stream);
    gvq_main<<<NROWS/TM, 256, 0, stream>>>(hidden, gu, w, b, cv, out, gavg);
    gvq_perp<<<1, 64, 0, stream>>>(gavg, out);
}

// Round 2
// 230.877 us; speedup vs baseline: 2.8676x; 2.8676x over previous
//
#include <hip/hip_runtime.h>
#include <math.h>

#define NROWS 32768
#define CDIM  512
#define G_    2
#define V_    320
#define NCOLS 640
#define DCODE 128

typedef short bf16x8 __attribute__((ext_vector_type(8)));
typedef float f32x16 __attribute__((ext_vector_type(16)));

__device__ __forceinline__ short f2bf(float f) {
    union { float f; unsigned u; } v; v.f = f;
    unsigned r = v.u + 0x7FFFu + ((v.u >> 16) & 1u);   // RTNE
    return (short)(r >> 16);
}

// W [512,640] f32 -> Wt [640,512] bf16 (coalesced read, scattered write; 1.3MB)
__global__ __launch_bounds__(256) void wprep(const float* __restrict__ w,
                                             short* __restrict__ wt) {
    int gid = blockIdx.x * 256 + threadIdx.x;     // 327680 = 512*640
    int k = gid / NCOLS;
    int n = gid - k * NCOLS;
    wt[(size_t)n * CDIM + k] = f2bf(w[(size_t)k * NCOLS + n]);
}

// Block: 64 rows. 4 waves: wave = (rowhalf<<1) | group. Wave tile: 32 rows x 320 cols.
// MFMA 32x32x16 bf16, 10 col-tiles, K=512 in 16-steps. B straight from L2 (Wt).
__global__ __launch_bounds__(256, 2) void gvq_main(
    const float* __restrict__ hidden,    // [32768,512] f32
    const float* __restrict__ gumbel_u,  // [65536,320] f32
    const short* __restrict__ wt,        // [640,512] bf16
    const float* __restrict__ bias,      // [640]
    const float* __restrict__ cv,        // [640,128]
    float* __restrict__ out,             // [32768,256] + perp scalar
    float* __restrict__ gavg)            // [640]
{
    __shared__ float savg[NCOLS];
    const int t    = threadIdx.x;
    const int wave = t >> 6;
    const int lane = t & 63;
    const int l31  = lane & 31;
    const int hw   = lane >> 5;
    const int g    = wave & 1;
    const int m0   = blockIdx.x * 64 + (wave >> 1) * 32;

    for (int i = t; i < NCOLS; i += 256) savg[i] = 0.f;
    __syncthreads();

    f32x16 acc[10];
    #pragma unroll
    for (int tt = 0; tt < 10; ++tt) {
        #pragma unroll
        for (int r = 0; r < 16; ++r) acc[tt][r] = 0.f;
    }

    const float* hrow  = hidden + (size_t)(m0 + l31) * CDIM + hw * 8;
    const short* wbase = wt + (size_t)(g * V_ + l31) * CDIM + hw * 8;

    for (int k0 = 0; k0 < CDIM; k0 += 16) {
        float4 h0 = *(const float4*)(hrow + k0);
        float4 h1 = *(const float4*)(hrow + k0 + 4);
        bf16x8 a;
        a[0]=f2bf(h0.x); a[1]=f2bf(h0.y); a[2]=f2bf(h0.z); a[3]=f2bf(h0.w);
        a[4]=f2bf(h1.x); a[5]=f2bf(h1.y); a[6]=f2bf(h1.z); a[7]=f2bf(h1.w);
        bf16x8 b[10];
        #pragma unroll
        for (int tt = 0; tt < 10; ++tt)
            b[tt] = *(const bf16x8*)(wbase + (size_t)tt * 32 * CDIM + k0);
        #pragma unroll
        for (int tt = 0; tt < 10; ++tt)
            acc[tt] = __builtin_amdgcn_mfma_f32_32x32x16_bf16(a, b[tt], acc[tt], 0, 0, 0);
    }

    // logits = acc + bias   (C/D layout: col = tt*32 + l31, row = (r&3)+8*(r>>2)+4*hw)
    #pragma unroll
    for (int tt = 0; tt < 10; ++tt) {
        float bv = bias[g * V_ + tt * 32 + l31];
        #pragma unroll
        for (int r = 0; r < 16; ++r) acc[tt][r] += bv;
    }

    // per-row softmax stats (reduce across 32 lanes of the half-wave)
    float mrow[16], inv[16];
    #pragma unroll
    for (int r = 0; r < 16; ++r) {
        float m = acc[0][r];
        #pragma unroll
        for (int tt = 1; tt < 10; ++tt) m = fmaxf(m, acc[tt][r]);
        #pragma unroll
        for (int o = 1; o <= 16; o <<= 1) m = fmaxf(m, __shfl_xor(m, o));
        mrow[r] = m;
        float ss = 0.f;
        #pragma unroll
        for (int tt = 0; tt < 10; ++tt) ss += __expf(acc[tt][r] - m);
        #pragma unroll
        for (int o = 1; o <= 16; o <<= 1) ss += __shfl_xor(ss, o);
        inv[r] = 1.f / ss;
    }

    // pass 2: prob accumulation + gumbel argmax + gather-write
    float cp[10];
    #pragma unroll
    for (int tt = 0; tt < 10; ++tt) cp[tt] = 0.f;

    #pragma unroll
    for (int r = 0; r < 16; ++r) {
        const int R = (r & 3) + 8 * (r >> 2) + 4 * hw;
        const size_t nrow = (size_t)(m0 + R);
        const float* up = gumbel_u + (nrow * 2 + (size_t)g) * V_;
        float best = -1e30f; int bcol = 0;
        #pragma unroll
        for (int tt = 0; tt < 10; ++tt) {
            float z = acc[tt][r];
            cp[tt] += __expf(z - mrow[r]) * inv[r];
            float u = up[tt * 32 + l31];
            float gum = -__logf(-__logf(u + 1e-10f) + 1e-10f);
            float nv = z + gum;
            if (nv > best) { best = nv; bcol = tt * 32 + l31; }  // ascending col => first-max
        }
        #pragma unroll
        for (int o = 1; o <= 16; o <<= 1) {
            float ov = __shfl_xor(best, o);
            int   oc = __shfl_xor(bcol, o);
            if (ov > best || (ov == best && oc < bcol)) { best = ov; bcol = oc; }
        }
        float4 cvv = *(const float4*)(cv + ((size_t)g * V_ + bcol) * DCODE + l31 * 4);
        *(float4*)(out + nrow * (G_ * DCODE) + g * DCODE + l31 * 4) = cvv;
    }

    #pragma unroll
    for (int tt = 0; tt < 10; ++tt)
        atomicAdd(&savg[g * V_ + tt * 32 + l31], cp[tt]);

    __syncthreads();
    for (int i = t; i < NCOLS; i += 256) atomicAdd(&gavg[i], savg[i]);
}

__global__ __launch_bounds__(64) void gvq_perp(const float* __restrict__ gavg,
                                               float* __restrict__ out)
{
    const int lane = threadIdx.x;
    float s0 = 0.f, s1 = 0.f;
    for (int v = lane; v < V_; v += 64) {
        float p0 = gavg[v]      * (1.f / NROWS);
        float p1 = gavg[V_ + v] * (1.f / NROWS);
        s0 += p0 * logf(p0 + 1e-7f);
        s1 += p1 * logf(p1 + 1e-7f);
    }
    #pragma unroll
    for (int o = 32; o >= 1; o >>= 1) {
        s0 += __shfl_xor(s0, o);
        s1 += __shfl_xor(s1, o);
    }
    if (lane == 0)
        out[(size_t)NROWS * (G_ * DCODE)] = expf(-s0) + expf(-s1);
}

extern "C" void kernel_launch(void* const* d_in, const int* in_sizes, int n_in,
                              void* d_out, int out_size, void* d_ws, size_t ws_size,
                              hipStream_t stream)
{
    const float* hidden = (const float*)d_in[0];
    const float* gu     = (const float*)d_in[1];
    const float* w      = (const float*)d_in[2];
    const float* b      = (const float*)d_in[3];
    const float* cv     = (const float*)d_in[4];
    float* out  = (float*)d_out;
    float* gavg = (float*)d_ws;                       // 640 f32
    short* wtb  = (short*)((char*)d_ws + 4096);       // 640*512 bf16 = 640KB

    hipMemsetAsync(d_ws, 0, NCOLS * sizeof(float), stream);
    wprep<<<(CDIM * NCOLS) / 256, 256, 0, stream>>>(w, wtb);
    gvq_main<<<NROWS / 64, 256, 0, stream>>>(hidden, gu, wtb, b, cv, out, gavg);
    gvq_perp<<<1, 64, 0, stream>>>(gavg, out);
}